// Round 7
// baseline (470.144 us; speedup 1.0000x reference)
//
#include <hip/hip_runtime.h>
#include <math.h>

// DeepMMD round 7: occupancy. r6 was latency-bound (VALUBusy 34%, Occ 19%,
// 2 blocks/CU). Per-quarter pipeline: acc(16)+da(16)+rowacc(16) -> ~80 VGPR
// (r5 precedent: 68) => 6 waves/SIMD, LDS 23KB => 6 blocks/CU. Staging is
// pure copy (Zh fp16 precomputed in mlp). Row-sums register-carried across
// quarters. MLP: 32 blocks x 256 thr, one row/thread (all lanes busy in the
// fp64 transcendental part) -> ~10us vs ~80us.

#define N_S 4096
#define LOG2E 1.4426950408889634

typedef _Float16 v8h __attribute__((ext_vector_type(8)));
typedef float v16f __attribute__((ext_vector_type(16)));
typedef float v2f __attribute__((ext_vector_type(2)));

union U16 { uint4 u; v8h h; };

// ---------------- MLP: 32 blocks x 256 thr, one row per thread ----------------
// Writes featsT[50][8192] fp32, Zh[8192][256] fp16, wOrg[8192]; zeroes D8, S.
__global__ __launch_bounds__(256)
void mlp_kernel(const float* __restrict__ X, const float* __restrict__ Y,
                const float* __restrict__ W1, const float* __restrict__ b1,
                const float* __restrict__ W2, const float* __restrict__ b2,
                const float* __restrict__ W3, const float* __restrict__ b3,
                const float* __restrict__ W4, const float* __restrict__ b4,
                const float* __restrict__ sq,
                float* __restrict__ featsT, _Float16* __restrict__ Zh,
                float* __restrict__ wOrg,
                float* __restrict__ D8, double* __restrict__ S)
{
    __shared__ double sW1[2560], sW2[100], sW3[100], sW4[500];
    __shared__ double sb1[10], sb2[10], sb3[10], sb4[50];
    int tid = threadIdx.x;
    int r = blockIdx.x * 256 + tid;        // 32*256 = 8192 rows exactly
    D8[r] = 0.0f;
    if (r < 4) S[r] = 0.0;

    for (int i = tid; i < 2560; i += 256) sW1[i] = (double)W1[i];
    if (tid < 100) { sW2[tid] = (double)W2[tid]; sW3[tid] = (double)W3[tid]; }
    for (int i = tid; i < 500; i += 256) sW4[i] = (double)W4[i];
    if (tid < 10) { sb1[tid] = (double)b1[tid]; sb2[tid] = (double)b2[tid]; sb3[tid] = (double)b3[tid]; }
    if (tid < 50) sb4[tid] = (double)b4[tid];
    __syncthreads();

    const float* xr = (r < N_S) ? (X + (size_t)r * 256) : (Y + (size_t)(r - N_S) * 256);

    double z[10];
#pragma unroll
    for (int j = 0; j < 10; ++j) z[j] = sb1[j];
    double nrm = 0.0;
    for (int k4 = 0; k4 < 256; k4 += 4) {
        float4 xv4 = *(const float4*)(xr + k4);
        union { _Float16 h[4]; uint2 u; } cv;
        cv.h[0] = (_Float16)xv4.x; cv.h[1] = (_Float16)xv4.y;
        cv.h[2] = (_Float16)xv4.z; cv.h[3] = (_Float16)xv4.w;
        *(uint2*)&Zh[(size_t)r * 256 + k4] = cv.u;
        double xv[4] = {(double)xv4.x, (double)xv4.y, (double)xv4.z, (double)xv4.w};
#pragma unroll
        for (int u = 0; u < 4; ++u) {
            nrm += xv[u] * xv[u];
#pragma unroll
            for (int j = 0; j < 10; ++j) z[j] += xv[u] * sW1[(k4 + u) * 10 + j];
        }
    }
#pragma unroll
    for (int j = 0; j < 10; ++j) z[j] = fmax(z[j], 0.0) + log1p(exp(-fabs(z[j])));

    double z2[10];
#pragma unroll
    for (int j = 0; j < 10; ++j) z2[j] = sb2[j];
#pragma unroll
    for (int k = 0; k < 10; ++k)
#pragma unroll
        for (int j = 0; j < 10; ++j) z2[j] += z[k] * sW2[k * 10 + j];
#pragma unroll
    for (int j = 0; j < 10; ++j) z2[j] = fmax(z2[j], 0.0) + log1p(exp(-fabs(z2[j])));

    double z3[10];
#pragma unroll
    for (int j = 0; j < 10; ++j) z3[j] = sb3[j];
#pragma unroll
    for (int k = 0; k < 10; ++k)
#pragma unroll
        for (int j = 0; j < 10; ++j) z3[j] += z2[k] * sW3[k * 10 + j];
#pragma unroll
    for (int j = 0; j < 10; ++j) z3[j] = fmax(z3[j], 0.0) + log1p(exp(-fabs(z3[j])));

    for (int j = 0; j < 50; ++j) {
        double f = sb4[j];
#pragma unroll
        for (int k = 0; k < 10; ++k) f += z3[k] * sW4[k * 50 + j];
        featsT[(size_t)j * 8192 + r] = (float)f;   // coalesced across lanes
    }
    double sqv = (double)sq[0];
    wOrg[r] = (float)exp2(-nrm * (LOG2E / (sqv * sqv)));
}

// ---------------- joint pairwise pass (per-quarter, low-VGPR) ----------------
__global__ __launch_bounds__(256)
void pair_kernel(const _Float16* __restrict__ Zh, const float* __restrict__ featsT,
                 const float* __restrict__ wOrg,
                 const float* __restrict__ ep, const float* __restrict__ sq,
                 const float* __restrict__ sph,
                 float* __restrict__ D8, double* __restrict__ S)
{
    // LDS: Ah 128 rows x 9 granules x 16B = 18432 | Bq 32 x 9 x 16 = 4608
    // stride-9 granule rows: lane quad = 9*l % 8 = l%8 -> conflict-free b128 (r6: 0 conflicts)
    __shared__ __align__(16) char smem[23040];
    uint4* Ah = (uint4*)smem;
    uint4* Bq = Ah + 1152;

    int tid = threadIdx.x;
    int lane = tid & 63, w = tid >> 6;
    int h = lane >> 5, l31 = lane & 31;

    // upper-triangle tile decode
    int L = blockIdx.x, it = 0, span = 64;
    while (L >= span) { L -= span; --span; ++it; }
    int jt = it + L;

    bool sameHalf = (jt < 32) || (it >= 32);
    bool isDiag = (it == jt);
    bool isTrace = (jt == it + 32);
    int region = (jt < 32) ? 0 : ((it >= 32) ? 1 : 2);
    float sgn = sameHalf ? 1.0f : -1.0f;
    int i0 = it * 128, j0 = jt * 128;

    double epd = (double)ep[0];
    double eps = 1.0 / (1.0 + exp(-epd));
    double sqv = (double)sq[0], spv = (double)sph[0];
    float cf = (float)(LOG2E / (spv * spv));
    float twoco = (float)(2.0 * LOG2E / (sqv * sqv));
    float epsv = (float)eps, ome = (float)(1.0 - eps);

    const _Float16* Arow = Zh + (size_t)i0 * 256;
    int fa_base = i0 + 32 * w + 4 * h;
    double bsum = 0.0, trd = 0.0;
    float rowacc[16];
#pragma unroll
    for (int q = 0; q < 16; ++q) rowacc[q] = 0.0f;

    for (int qt = 0; qt < 4; ++qt) {
        int j0q = j0 + 32 * qt;
        const _Float16* Brow = Zh + (size_t)j0q * 256;

        // ---- phase A: fp16 MFMA org dot (wave w: 32 rows x quarter's 32 cols) ----
        v16f acc = (v16f)(0.0f);
        for (int kb = 0; kb < 256; kb += 64) {
            __syncthreads();   // prior reads (frag or F-phase none) done
            for (int idx = tid; idx < 1280; idx += 256) {
                if (idx < 1024) {
                    int rr = idx >> 3, g = idx & 7;
                    Ah[rr * 9 + g] = *(const uint4*)(Arow + (size_t)rr * 256 + kb + g * 8);
                } else {
                    int t = idx - 1024;
                    int rr = t >> 3, g = t & 7;
                    Bq[rr * 9 + g] = *(const uint4*)(Brow + (size_t)rr * 256 + kb + g * 8);
                }
            }
            __syncthreads();
#pragma unroll
            for (int ks = 0; ks < 4; ++ks) {
                int g = 2 * ks + h;
                U16 ta, tb;
                ta.u = Ah[(32 * w + l31) * 9 + g];
                tb.u = Bq[l31 * 9 + g];
                acc = __builtin_amdgcn_mfma_f32_32x32x16_f16(ta.h, tb.h, acc, 0, 0, 0);
            }
        }

        // ---- phase F: exact fp32 feature dist (C-layout: rows 4h+{0-3,8-11,16-19,24-27}+32w, col l31) ----
        v2f da[8];
#pragma unroll
        for (int j = 0; j < 8; ++j) da[j] = (v2f)(0.0f);
        for (int k = 0; k < 50; ++k) {
            const float* fr = featsT + (size_t)k * 8192;
            float4 a0 = *(const float4*)(fr + fa_base);
            float4 a1 = *(const float4*)(fr + fa_base + 8);
            float4 a2 = *(const float4*)(fr + fa_base + 16);
            float4 a3 = *(const float4*)(fr + fa_base + 24);
            float b = fr[j0q + l31];
            v2f bb; bb[0] = b; bb[1] = b;
            v2f ap[8];
            ap[0][0] = a0.x; ap[0][1] = a0.y; ap[1][0] = a0.z; ap[1][1] = a0.w;
            ap[2][0] = a1.x; ap[2][1] = a1.y; ap[3][0] = a1.z; ap[3][1] = a1.w;
            ap[4][0] = a2.x; ap[4][1] = a2.y; ap[5][0] = a2.z; ap[5][1] = a2.w;
            ap[6][0] = a3.x; ap[6][1] = a3.y; ap[7][0] = a3.z; ap[7][1] = a3.w;
#pragma unroll
            for (int j = 0; j < 8; ++j) {
                v2f t = ap[j] - bb;
                da[j] = t * t + da[j];
            }
        }

        // ---- epilogue: no LDS, no barriers ----
        float wb = wOrg[j0q + l31];
        float qsum = 0.0f, colacc = 0.0f;
#pragma unroll
        for (int q = 0; q < 16; ++q) {
            int row = 32 * w + 4 * h + (q & 3) + 8 * (q >> 2);
            float wa = wOrg[i0 + row];
            float e1 = exp2f(acc[q] * twoco);
            float e2 = exp2f(-da[q >> 1][q & 1] * cf);
            float kv = wa * wb * e1 * (ome * e2 + epsv);
            int col = 32 * qt + l31;
            if (isDiag && row == col) kv = 0.0f;
            if (isTrace) { if (row == col) trd += (double)kv; }
            qsum += kv;
            colacc += kv;
            rowacc[q] += kv;
        }
        bsum += (double)qsum;
        if (!isDiag) {
            float v = colacc + __shfl_xor(colacc, 32, 64);
            if (h == 0) atomicAdd(&D8[j0q + l31], sgn * v);
        }
    }

    // row sums: one butterfly set per tile (rowacc carried across quarters)
#pragma unroll
    for (int q = 0; q < 16; ++q) {
        float rs = rowacc[q];
#pragma unroll
        for (int m = 1; m < 32; m <<= 1) rs += __shfl_xor(rs, m, 64);
        if (l31 == q) {
            int row = 32 * w + 4 * h + (q & 3) + 8 * (q >> 2);
            atomicAdd(&D8[i0 + row], sgn * rs);
        }
    }

    // block totals
#pragma unroll
    for (int m = 1; m < 64; m <<= 1) bsum += __shfl_xor(bsum, m, 64);
    __shared__ double wred[4];
    if (lane == 0) wred[w] = bsum;
    __syncthreads();
    if (tid == 0) {
        double wgt = (sameHalf && !isDiag) ? 2.0 : 1.0;
        atomicAdd(&S[region], wgt * (wred[0] + wred[1] + wred[2] + wred[3]));
    }
    if (isTrace) {
#pragma unroll
        for (int m = 1; m < 64; m <<= 1) trd += __shfl_xor(trd, m, 64);
        if (lane == 0) atomicAdd(&S[3], trd);
    }
}

// ---------------- final scalar assembly ----------------
__global__ __launch_bounds__(256)
void final_kernel(const float* __restrict__ D8, const double* __restrict__ S,
                  float* __restrict__ out)
{
    __shared__ double buf[512];
    int tid = threadIdx.x;
    double sD = 0, sD2 = 0;
    for (int i = tid; i < 4096; i += 256) {
        double d = (double)D8[i] + (double)D8[i + 4096];
        sD += d; sD2 += d * d;
    }
    buf[tid] = sD; buf[256 + tid] = sD2;
    __syncthreads();
    for (int s = 128; s > 0; s >>= 1) {
        if (tid < s) { buf[tid] += buf[tid + s]; buf[256 + tid] += buf[256 + tid + s]; }
        __syncthreads();
    }
    if (tid == 0) {
        double n = (double)N_S, D = n * (n - 1.0);
        double xx = S[0] / D, yy = S[1] / D, xy = (S[2] - S[3]) / D;
        double mmd2 = xx - 2.0 * xy + yy;
        double sumd = buf[0], sumd2 = buf[256];
        double sumh = 2.0 * n + sumd;                    // hs_i = 2 + delta_i
        double sumhs2 = 4.0 * n + 4.0 * sumd + sumd2;
        double n3 = n * n * n, n4 = n3 * n;
        double var = 4.0 / n3 * sumhs2 - 4.0 / n4 * sumh * sumh + 1e-8;
        out[0] = (float)mmd2;
        out[1] = (float)var;
    }
}

extern "C" void kernel_launch(void* const* d_in, const int* in_sizes, int n_in,
                              void* d_out, int out_size, void* d_ws, size_t ws_size,
                              hipStream_t stream)
{
    const float* X   = (const float*)d_in[0];
    const float* Y   = (const float*)d_in[1];
    const float* W1  = (const float*)d_in[2];
    const float* b1  = (const float*)d_in[3];
    const float* W2  = (const float*)d_in[4];
    const float* b2  = (const float*)d_in[5];
    const float* W3  = (const float*)d_in[6];
    const float* b3  = (const float*)d_in[7];
    const float* W4  = (const float*)d_in[8];
    const float* b4  = (const float*)d_in[9];
    const float* ep  = (const float*)d_in[10];
    const float* sq  = (const float*)d_in[11];
    const float* sph = (const float*)d_in[12];
    float* out = (float*)d_out;

    char* ws = (char*)d_ws;
    float*     featsT = (float*)ws;                   // 50*8192*4 = 1638400
    _Float16*  Zh     = (_Float16*)(ws + 1638400);    // 8192*256*2 = 4194304
    float*     wOrg   = (float*)(ws + 5832704);       // 32768
    float*     D8     = (float*)(ws + 5865472);       // 32768
    double*    S      = (double*)(ws + 5898240);      // 32 (Sxx, Syy, Sxy, trace)

    mlp_kernel<<<32, 256, 0, stream>>>(X, Y, W1, b1, W2, b2, W3, b3, W4, b4,
                                       sq, featsT, Zh, wOrg, D8, S);

    pair_kernel<<<2080, 256, 0, stream>>>(Zh, featsT, wOrg, ep, sq, sph, D8, S);

    final_kernel<<<1, 256, 0, stream>>>(D8, S, out);
}